// Round 20
// baseline (231.761 us; speedup 1.0000x reference)
//
#include <hip/hip_runtime.h>
#include <math.h>

#define NPIX 16384
#define CH 256
#define MDIM 32
#define NB 8
#define EPSF 1e-6f
#define SPLIT 8
#define KCH (NPIX / SPLIT)   // 2048

// ws BYTE layout (all 2-byte intermediates fp16)
//   ATTB @ 0        : fp16 attn·gc [B][C][D]  1,048,576 B
//   KVTB @ 1048576  : fp16 KV^T [B][C][M]       131,072 B
//   KSUM @ 1179648  : f32 [B][M]                  1,024 B
//   XKR  @ 1180672  : f32 [B][M][D]             262,144 B   (memset w/ KSUM)
//   WQB  @ 1442816  : fp16 [M][C] 16384 B
//   WKB  @ 1459200  : fp16 [M][C] 16384 B
//   QG   @ 1508352  : fp16 Q [B][N][M]         8,388,608 B  (un-normalized)
// d_out doubles as scratch before k_final overwrites it (stream-ordered):
//   [0, 33554432) bytes           xkpart fp16 [B][T=256][M][D=256]
//   [67108864, 83886080) bytes    enpart f32 [SPLIT=8][B][C][C]
#define XKPART_F32OFF 16777216ull   // float offset of enpart in d_out

#define GRAM_BLKS 192               // 3 * SPLIT * NB
#define KX_BLKS   2048              // 256 * NB

typedef short short4v __attribute__((ext_vector_type(4)));
typedef short short8 __attribute__((ext_vector_type(8)));
typedef _Float16 half8 __attribute__((ext_vector_type(8)));
typedef float f32x4 __attribute__((ext_vector_type(4)));

__device__ inline unsigned short f2h(float v) {
    return __builtin_bit_cast(unsigned short, (_Float16)v);   // 1 v_cvt op
}
__device__ inline float h2f(unsigned short h) {
    return (float)__builtin_bit_cast(_Float16, h);
}

__global__ void k_prep(const float* __restrict__ wq, const float* __restrict__ wk,
                       unsigned short* __restrict__ WQB, unsigned short* __restrict__ WKB)
{
    int i = blockIdx.x * 256 + threadIdx.x;   // 8192 total
    WQB[i] = f2h(wq[i]);
    WKB[i] = f2h(wk[i]);
}

// FUSED launch 1: blocks [0,192) = gram (SPLIT=8, 2x K-work each),
// [192,2240) = kx.  2240 blocks / 1024 slots: gram (~2x duration) starts
// first and finishes ~when the 2.2-round kx stream does — balanced fill
// (was 2.375 rounds with a 60%-idle tail at SPLIT=16).
// Gram XCD swizzle: bid -> (xcd=bid&7, slot=bid>>3); grp=xcd*8+slot/3;
// tile=slot%3; b=grp>>3==xcd (each XCD owns ONE batch), sp=grp&7.
__global__ __launch_bounds__(256, 4) void k_work1(
    const float* __restrict__ x,
    const unsigned short* __restrict__ WKB, const unsigned short* __restrict__ WQB,
    const float* __restrict__ bk, const float* __restrict__ bq,
    unsigned short* __restrict__ xkpart, float* __restrict__ Ksum,
    unsigned short* __restrict__ Qg, float* __restrict__ enpart)
{
    __shared__ unsigned short ldsbuf[20480];   // 40960 B
    const int bid = blockIdx.x;
    const int tid = threadIdx.x;

    if (bid < GRAM_BLKS) {
        // ================= GRAM (staged fp16 MFMA, symmetry-aware) =========
        unsigned short* As = ldsbuf;            // 128*72
        unsigned short* Bs = ldsbuf + 9216;     // 128*72
        const int xcd = bid & 7, slot = bid >> 3;      // 24 slots per XCD
        const int grp = xcd * 8 + slot / 3;            // [0,64)
        const int tile = slot % 3;
        const int sp = grp & 7, b = grp >> 3;
        const int rt = (tile == 2) ? 1 : 0;
        const int ct = (tile == 0) ? 0 : 1;
        const bool diag = (rt == ct);
        const int r0 = rt * 128, c0 = ct * 128;
        const float* xb = x + (size_t)b * CH * NPIX;
        const int k0base = sp * KCH;

        unsigned short* Bs_p = diag ? As : Bs;

        const int wave = tid >> 6, lane = tid & 63;
        const int wr = wave >> 1, wc = wave & 1;

        f32x4 acc[4][4];
        #pragma unroll
        for (int i = 0; i < 4; ++i)
            #pragma unroll
            for (int j = 0; j < 4; ++j)
                acc[i][j] = (f32x4){0.f, 0.f, 0.f, 0.f};

        const int oct = tid & 7;
        const int frow = tid >> 3;

        for (int kk = 0; kk < KCH; kk += 64) {
            __syncthreads();
            const int k0 = k0base + kk;
            #pragma unroll
            for (int half = 0; half < 2; ++half) {
                if (half && diag) continue;
                const int rowbase = half ? c0 : r0;
                unsigned short* Hs = half ? Bs : As;
                #pragma unroll
                for (int s = 0; s < 4; ++s) {
                    const int r = frow + s * 32;
                    const float* src = xb + (size_t)(rowbase + r) * NPIX + k0 + oct * 8;
                    float4 v0 = *(const float4*)src;
                    float4 v1 = *(const float4*)(src + 4);
                    float vv[8] = {v0.x, v0.y, v0.z, v0.w, v1.x, v1.y, v1.z, v1.w};
                    short8 p;
                    #pragma unroll
                    for (int e = 0; e < 8; ++e) p[e] = (short)f2h(vv[e]);
                    *(short8*)&Hs[r * 72 + oct * 8] = p;
                }
            }
            __syncthreads();

            #pragma unroll
            for (int ks2 = 0; ks2 < 2; ++ks2) {
                short8 a4[4], b4[4];
                const int rbase = wr * 64 + (lane & 15);
                const int cbase = wc * 64 + (lane & 15);
                const int koff = ks2 * 32 + (lane >> 4) * 8;
                #pragma unroll
                for (int f = 0; f < 4; ++f) {
                    a4[f] = *(const short8*)&As[(rbase + f * 16) * 72 + koff];
                    b4[f] = *(const short8*)&Bs_p[(cbase + f * 16) * 72 + koff];
                }
                #pragma unroll
                for (int i = 0; i < 4; ++i)
                    #pragma unroll
                    for (int j = 0; j < 4; ++j)
                        acc[i][j] = __builtin_amdgcn_mfma_f32_16x16x32_f16(
                            __builtin_bit_cast(half8, a4[i]),
                            __builtin_bit_cast(half8, b4[j]), acc[i][j], 0, 0, 0);
            }
        }

        float* ep = enpart + (size_t)(sp * NB + b) * (CH * CH);
        const int rw = (lane >> 4) * 4;
        const int cw = lane & 15;
        #pragma unroll
        for (int i = 0; i < 4; ++i)
            #pragma unroll
            for (int j = 0; j < 4; ++j) {
                const int row = r0 + wr * 64 + i * 16 + rw;
                const int col = c0 + wc * 64 + j * 16 + cw;
                #pragma unroll
                for (int q = 0; q < 4; ++q) {
                    float v = acc[i][j][q];
                    ep[(size_t)(row + q) * CH + col] = v;
                    if (!diag) ep[(size_t)col * CH + (row + q)] = v;
                }
            }
    } else {
        // ================= KX (K+Q conv + XK partial) ======================
        unsigned short* xs  = ldsbuf;            // CH*72 = 18432 shorts
        unsigned short* ksm = ldsbuf + 18432;    // MDIM*64 = 2048 shorts
        const int u = bid - GRAM_BLKS;
        const int b = u >> 8, t = u & 255;
        const int n0 = t * 64;
        const int w = tid >> 6, l = tid & 63;
        const int li = l & 15, lg = l >> 4;
        const float* xb = x + (size_t)b * CH * NPIX;

        #pragma unroll
        for (int s = 0; s < 8; ++s) {
            int e8 = tid + s * 256;
            int c = e8 >> 3, j8 = e8 & 7;
            const float* src = xb + (size_t)c * NPIX + n0 + j8 * 8;
            float4 v0 = *(const float4*)src;
            float4 v1 = *(const float4*)(src + 4);
            float vv[8] = {v0.x, v0.y, v0.z, v0.w, v1.x, v1.y, v1.z, v1.w};
            short8 p;
            #pragma unroll
            for (int e = 0; e < 8; ++e) p[e] = (short)f2h(vv[e]);
            const int g = j8 ^ (c & 7) ^ ((c >> 3) & 7);
            *(short8*)&xs[c * 72 + g * 8] = p;
        }
        __syncthreads();

        {   // K + Q via f16 MFMA; wave w covers n = w*16 + li
            f32x4 accK[2], accQ[2];
            #pragma unroll
            for (int i = 0; i < 2; ++i) {
                accK[i] = (f32x4){0.f, 0.f, 0.f, 0.f};
                accQ[i] = (f32x4){0.f, 0.f, 0.f, 0.f};
            }
            const int n = w * 16 + li;
            const int gn = n >> 3, inn = n & 7;
            #pragma unroll
            for (int kc = 0; kc < 8; ++kc) {
                short8 bxw;
                #pragma unroll
                for (int e = 0; e < 8; ++e) {
                    const int d = kc * 32 + lg * 8 + e;
                    const int g = gn ^ e ^ ((kc * 4 + lg) & 7);
                    bxw[e] = (short)xs[d * 72 + g * 8 + inn];
                }
                half8 bx = __builtin_bit_cast(half8, bxw);
                #pragma unroll
                for (int i = 0; i < 2; ++i) {
                    const size_t wo = (size_t)(i * 16 + li) * CH + kc * 32 + lg * 8;
                    half8 kw = __builtin_bit_cast(half8, *(const short8*)(WKB + wo));
                    half8 qw = __builtin_bit_cast(half8, *(const short8*)(WQB + wo));
                    accK[i] = __builtin_amdgcn_mfma_f32_16x16x32_f16(kw, bx, accK[i], 0, 0, 0);
                    accQ[i] = __builtin_amdgcn_mfma_f32_16x16x32_f16(qw, bx, accQ[i], 0, 0, 0);
                }
            }
            unsigned short* qp = Qg + ((size_t)b * NPIX + n0 + n) * MDIM;
            #pragma unroll
            for (int i = 0; i < 2; ++i) {
                short4v q4;
                #pragma unroll
                for (int q = 0; q < 4; ++q) {
                    const int m = i * 16 + lg * 4 + q;
                    float kv = accK[i][q] + bk[m];
                    kv = fmaxf(kv, 0.f) + log1pf(expf(-fabsf(kv)));  // softplus
                    ksm[m * 64 + (n ^ ((m & 7) << 3))] = f2h(kv);
                    float qv = accQ[i][q] + bq[m];
                    qv = fmaxf(qv, 0.f) + log1pf(expf(-fabsf(qv)));  // softplus
                    q4[q] = (short)f2h(qv);
                }
                *(short4v*)(qp + i * 16 + lg * 4) = q4;
            }
        }
        __syncthreads();

        if (tid < MDIM) {
            float s = 0.f;
            #pragma unroll
            for (int j = 0; j < 64; ++j)
                s += h2f(ksm[tid * 64 + (j ^ ((tid & 7) << 3))]);
            atomicAdd(&Ksum[b * MDIM + tid], s);
        }

        f32x4 axk[4][2];
        #pragma unroll
        for (int i = 0; i < 4; ++i)
            #pragma unroll
            for (int j = 0; j < 2; ++j) axk[i][j] = (f32x4){0.f, 0.f, 0.f, 0.f};

        #pragma unroll
        for (int ks2 = 0; ks2 < 2; ++ks2) {
            const int nc = ks2 * 32 + lg * 8;
            half8 kfr[2];
            #pragma unroll
            for (int j = 0; j < 2; ++j) {
                const int m = j * 16 + li;
                kfr[j] = __builtin_bit_cast(half8,
                    *(const short8*)&ksm[m * 64 + (nc ^ ((m & 7) << 3))]);
            }
            #pragma unroll
            for (int i = 0; i < 4; ++i) {
                const int d = w * 64 + i * 16 + li;
                const int g = (nc >> 3) ^ (d & 7) ^ ((d >> 3) & 7);
                half8 xf = __builtin_bit_cast(half8, *(const short8*)&xs[d * 72 + g * 8]);
                #pragma unroll
                for (int j = 0; j < 2; ++j)
                    axk[i][j] = __builtin_amdgcn_mfma_f32_16x16x32_f16(xf, kfr[j], axk[i][j], 0, 0, 0);
            }
        }

        unsigned short* xkp = xkpart + (size_t)(b * 256 + t) * MDIM * CH;
        #pragma unroll
        for (int i = 0; i < 4; ++i)
            #pragma unroll
            for (int j = 0; j < 2; ++j) {
                short4v pk;
                #pragma unroll
                for (int q = 0; q < 4; ++q) pk[q] = (short)f2h(axk[i][j][q]);
                *(short4v*)(xkp + (size_t)(j * 16 + li) * CH + w * 64 + i * 16 + lg * 4) = pk;
            }
    }
}

// FUSED launch 2: blocks [0,1024) = xkreduce, [1024,3072) = softmax.
__global__ void k_work2(const unsigned short* __restrict__ xkpart,
                        float* __restrict__ XKR,
                        const float* __restrict__ enpart,
                        const float* __restrict__ gc,
                        unsigned short* __restrict__ attnb)
{
    __shared__ float red[8];
    const int bid = blockIdx.x;
    if (bid < 1024) {
        // ---- xkreduce: 4-way t-split over fp16 partials ----
        const int bx = bid & 255;
        const int b = bx >> 5, m = bx & 31, d = threadIdx.x;
        const int t0 = (bid >> 8) * 64;
        float s = 0.f;
        #pragma unroll 4
        for (int t = t0; t < t0 + 64; ++t)
            s += h2f(xkpart[(((size_t)b * 256 + t) * MDIM + m) * CH + d]);
        atomicAdd(&XKR[((size_t)b * MDIM + m) * CH + d], s);
    } else {
        // ---- softmin over summed partials; emits fp16 (gc*attn) ----
        const int bid2 = bid - 1024;
        const int b = bid2 >> 8, c = bid2 & 255;
        const int d = threadIdx.x;
        float e = 0.f;
        #pragma unroll
        for (int sp = 0; sp < SPLIT; ++sp)
            e += enpart[(size_t)(sp * NB + b) * (CH * CH) + (size_t)c * CH + d];
        float mn = e;
        #pragma unroll
        for (int o = 1; o < 64; o <<= 1) mn = fminf(mn, __shfl_xor(mn, o));
        if ((d & 63) == 0) red[d >> 6] = mn;
        __syncthreads();
        mn = fminf(fminf(red[0], red[1]), fminf(red[2], red[3]));
        float w = expf(mn - e);
        float s = w;
        #pragma unroll
        for (int o = 1; o < 64; o <<= 1) s += __shfl_xor(s, o);
        if ((d & 63) == 0) red[4 + (d >> 6)] = s;
        __syncthreads();
        s = red[4] + red[5] + red[6] + red[7];
        attnb[((size_t)(b * CH) + c) * CH + d] = f2h(gc[0] * w / s);
    }
}

// KV^T[c][m] = sum_d wv[c][d]*XKR[m][d] + bv[c]*Ksum[m] — f16 MFMA.
__global__ void k_kv(const float* __restrict__ wv, const float* __restrict__ bv,
                     const float* __restrict__ XKR, const float* __restrict__ Ksum,
                     unsigned short* __restrict__ KVTb) {
    const int b = blockIdx.x, tid = threadIdx.x;
    const int w = tid >> 6, l = tid & 63;
    const int li = l & 15, lg = l >> 4;

    f32x4 acc[4][2];   // i: c-16blocks in wave's 64c; j: m-16blocks
    #pragma unroll
    for (int i = 0; i < 4; ++i)
        #pragma unroll
        for (int j = 0; j < 2; ++j) acc[i][j] = (f32x4){0.f, 0.f, 0.f, 0.f};

    for (int kk = 0; kk < CH; kk += 32) {
        half8 bfr[2];
        #pragma unroll
        for (int j = 0; j < 2; ++j) {
            const int m = j * 16 + li;
            const float* sp = XKR + ((size_t)b * MDIM + m) * CH + kk + lg * 8;
            float4 v0 = *(const float4*)sp;
            float4 v1 = *(const float4*)(sp + 4);
            bfr[j][0] = (_Float16)v0.x; bfr[j][1] = (_Float16)v0.y;
            bfr[j][2] = (_Float16)v0.z; bfr[j][3] = (_Float16)v0.w;
            bfr[j][4] = (_Float16)v1.x; bfr[j][5] = (_Float16)v1.y;
            bfr[j][6] = (_Float16)v1.z; bfr[j][7] = (_Float16)v1.w;
        }
        #pragma unroll
        for (int i = 0; i < 4; ++i) {
            const int c = w * 64 + i * 16 + li;
            const float* wp = wv + (size_t)c * CH + kk + lg * 8;
            float4 w0 = *(const float4*)wp;
            float4 w1 = *(const float4*)(wp + 4);
            half8 afr;
            afr[0] = (_Float16)w0.x; afr[1] = (_Float16)w0.y;
            afr[2] = (_Float16)w0.z; afr[3] = (_Float16)w0.w;
            afr[4] = (_Float16)w1.x; afr[5] = (_Float16)w1.y;
            afr[6] = (_Float16)w1.z; afr[7] = (_Float16)w1.w;
            #pragma unroll
            for (int j = 0; j < 2; ++j)
                acc[i][j] = __builtin_amdgcn_mfma_f32_16x16x32_f16(afr, bfr[j], acc[i][j], 0, 0, 0);
        }
    }

    // D: row = c (lg*4+q within 16-block), col = m (li)
    #pragma unroll
    for (int i = 0; i < 4; ++i)
        #pragma unroll
        for (int j = 0; j < 2; ++j) {
            const int m = j * 16 + li;
            const float ks = Ksum[b * MDIM + m];
            #pragma unroll
            for (int q = 0; q < 4; ++q) {
                const int c = w * 64 + i * 16 + lg * 4 + q;
                KVTb[((size_t)b * CH + c) * MDIM + m] =
                    f2h(acc[i][j][q] + bv[c] * ks);
            }
        }
}

// out = x + (nrm·Q)^T·KV + (gc·attn)·X — fp16 operands, f16 MFMAs.
__global__ __launch_bounds__(256, 4) void k_final(
    const float* __restrict__ x, const unsigned short* __restrict__ Qg,
    const unsigned short* __restrict__ KVTb, const float* __restrict__ Ksum,
    const unsigned short* __restrict__ attnb, const float* __restrict__ gk,
    float* __restrict__ out)
{
    __shared__ uint2 xsTv[4096];            // 32 KB: fp16 xT [n=64][d=256] swizzled
    unsigned char* xsT = (unsigned char*)xsTv;
    const int b = blockIdx.y, n0 = blockIdx.x * 64, tid = threadIdx.x;
    const int w = tid >> 6, l = tid & 63;
    const int li = l & 15, lg = l >> 4;
    const float* xb = x + (size_t)b * CH * NPIX;

    // ---- issue Q fragment loads + Ksum loads (in flight during staging) ----
    short8 qb[4];
    #pragma unroll
    for (int j = 0; j < 4; ++j)
        qb[j] = *(const short8*)(Qg +
            ((size_t)b * NPIX + n0 + j * 16 + li) * MDIM + lg * 8);
    float4 ks0 = *(const float4*)(Ksum + b * MDIM + lg * 8);
    float4 ks1 = *(const float4*)(Ksum + b * MDIM + lg * 8 + 4);
    const float kse[8] = {ks0.x + EPSF, ks0.y + EPSF, ks0.z + EPSF, ks0.w + EPSF,
                          ks1.x + EPSF, ks1.y + EPSF, ks1.z + EPSF, ks1.w + EPSF};

    // ---- stage xT ----
    {
        const int n4 = li * 4;
        const bool o1 = lg & 1, o2 = (lg >> 1) & 1;
        #pragma unroll 4
        for (int p = 0; p < 16; ++p) {
            const int d0 = w * 64 + p * 4;
            float4 vv = *(const float4*)(xb + (size_t)(d0 + lg) * NPIX + n0 + n4);
            float v0 = vv.x, v1 = vv.y, v2 = vv.z, v3 = vv.w;
            float r1 = __shfl_xor(o1 ? v0 : v1, 16);
            float r2 = __shfl_xor(o1 ? v2 : v3, 16);
            float a0 = o1 ? r1 : v0, a1 = o1 ? v1 : r1;
            float a2 = o1 ? r2 : v2, a3 = o1 ? v3 : r2;
            float r3 = __shfl_xor(o2 ? a0 : a2, 32);
            float r4 = __shfl_xor(o2 ? a1 : a3, 32);
            float b0 = o2 ? r3 : a0, b1 = o2 ? r4 : a1;
            float b2 = o2 ? a2 : r3, b3 = o2 ? a3 : r4;
            const int nl = n4 + lg;
            unsigned lo = (unsigned)f2h(b0) | ((unsigned)f2h(b1) << 16);
            unsigned hi = (unsigned)f2h(b2) | ((unsigned)f2h(b3) << 16);
            const int off = nl * 512 +
                ((2 * d0) ^ ((nl & 7) << 4) ^ (((nl >> 3) & 1) << 3));
            *(uint2*)(xsT + off) = make_uint2(lo, hi);
        }
    }

    f32x4 acc[4][4];   // acc[i][j]: rows = n-block j, cols = c-block i
    #pragma unroll
    for (int i = 0; i < 4; ++i)
        #pragma unroll
        for (int j = 0; j < 4; ++j)
            acc[i][j] = (f32x4){0.f, 0.f, 0.f, 0.f};

    // ---- KAM (pre-barrier: no LDS dependence) ----
    {
        const float gkv = gk[0];
        half8 qs[4];
        #pragma unroll
        for (int j = 0; j < 4; ++j) {
            float qf[8];
            float den = 0.f;
            #pragma unroll
            for (int e = 0; e < 8; ++e) {
                qf[e] = h2f((unsigned short)qb[j][e]);
                den = fmaf(qf[e], kse[e], den);
            }
            den += __shfl_xor(den, 16);
            den += __shfl_xor(den, 32);
            const float nrm = gkv / den;
            #pragma unroll
            for (int e = 0; e < 8; ++e) qs[j][e] = (_Float16)(qf[e] * nrm);
        }
        #pragma unroll
        for (int i = 0; i < 4; ++i) {
            half8 ka = __builtin_bit_cast(half8, *(const short8*)(KVTb +
                ((size_t)b * CH + w * 64 + i * 16 + li) * MDIM + lg * 8));
            #pragma unroll
            for (int j = 0; j < 4; ++j)
                acc[i][j] = __builtin_amdgcn_mfma_f32_16x16x32_f16(qs[j], ka, acc[i][j], 0, 0, 0);
        }
    }
    __syncthreads();

    // ---- CAM: acc += X^T · (gc·attn)^T ----
    const unsigned short* ab = attnb + (size_t)b * CH * CH;
    for (int kk = 0; kk < CH; kk += 32) {
        half8 bx[4];
        #pragma unroll
        for (int j = 0; j < 4; ++j) {
            const int nf = j * 16 + li;
            const int d2 = 2 * (kk + lg * 8);
            const int sw = ((nf & 7) << 4) ^ (((nf >> 3) & 1) << 3);
            uint2 h0 = *(const uint2*)(xsT + nf * 512 + (d2 ^ sw));
            uint2 h1 = *(const uint2*)(xsT + nf * 512 + ((d2 + 8) ^ sw));
            int4 tmp = make_int4(h0.x, h0.y, h1.x, h1.y);
            bx[j] = __builtin_bit_cast(half8, tmp);
        }
        #pragma unroll
        for (int i = 0; i < 4; ++i) {
            half8 af = __builtin_bit_cast(half8, *(const short8*)(ab +
                (size_t)(w * 64 + i * 16 + li) * CH + kk + lg * 8));
            #pragma unroll
            for (int j = 0; j < 4; ++j)
                acc[i][j] = __builtin_amdgcn_mfma_f32_16x16x32_f16(bx[j], af, acc[i][j], 0, 0, 0);
        }
    }

    // ---- epilogue: out = x + acc, float4 per (i,j) ----
    float* outb = out + (size_t)b * CH * NPIX;
    #pragma unroll
    for (int i = 0; i < 4; ++i) {
        const int c = w * 64 + i * 16 + li;
        #pragma unroll
        for (int j = 0; j < 4; ++j) {
            const size_t idx = (size_t)c * NPIX + n0 + j * 16 + lg * 4;
            float4 xv = *(const float4*)(xb + idx);
            float4 v = make_float4(xv.x + acc[i][j][0], xv.y + acc[i][j][1],
                                   xv.z + acc[i][j][2], xv.w + acc[i][j][3]);
            *(float4*)(outb + idx) = v;
        }
    }
}

extern "C" void kernel_launch(void* const* d_in, const int* in_sizes, int n_in,
                              void* d_out, int out_size, void* d_ws, size_t ws_size,
                              hipStream_t stream)
{
    const float* x  = (const float*)d_in[0];
    const float* wq = (const float*)d_in[1];
    const float* bq = (const float*)d_in[2];
    const float* wk = (const float*)d_in[3];
    const float* bk = (const float*)d_in[4];
    const float* wv = (const float*)d_in[5];
    const float* bv = (const float*)d_in[6];
    const float* gk = (const float*)d_in[7];
    const float* gc = (const float*)d_in[8];
    float* out = (float*)d_out;
    char* wsb = (char*)d_ws;

    unsigned short* ATTB = (unsigned short*)(wsb);
    unsigned short* KVTB = (unsigned short*)(wsb + 1048576);
    float* KSUM = (float*)(wsb + 1179648);
    float* XKR  = (float*)(wsb + 1180672);
    unsigned short* WQB = (unsigned short*)(wsb + 1442816);
    unsigned short* WKB = (unsigned short*)(wsb + 1459200);
    unsigned short* QG  = (unsigned short*)(wsb + 1508352);

    unsigned short* xkpart = (unsigned short*)out;   // d_out scratch (fp16 partials)
    float* enpart = out + XKPART_F32OFF;

    // zero KSUM (1 KB) + XKR (256 KB) — contiguous
    hipMemsetAsync(KSUM, 0, 1024 + 262144, stream);

    k_prep<<<dim3(32), dim3(256), 0, stream>>>(wq, wk, WQB, WKB);
    k_work1<<<dim3(GRAM_BLKS + KX_BLKS), dim3(256), 0, stream>>>(
        x, WKB, WQB, bk, bq, xkpart, KSUM, QG, enpart);
    k_work2<<<dim3(3072), dim3(256), 0, stream>>>(xkpart, XKR, enpart, gc, ATTB);
    k_kv<<<dim3(NB), dim3(256), 0, stream>>>(wv, bv, XKR, KSUM, KVTB);
    k_final<<<dim3(NPIX / 64, NB), dim3(256), 0, stream>>>(x, QG, KVTB, KSUM,
                                                           ATTB, gk, out);
}

// Round 21
// 219.930 us; speedup vs baseline: 1.0538x; 1.0538x over previous
//
#include <hip/hip_runtime.h>
#include <math.h>

#define NPIX 16384
#define CH 256
#define MDIM 32
#define NB 8
#define EPSF 1e-6f
#define SPLIT 16
#define KCH (NPIX / SPLIT)   // 1024

// ws BYTE layout (all 2-byte intermediates fp16)
//   ATTB @ 0        : fp16 attn·gc [B][C][D]  1,048,576 B
//   KVTB @ 1048576  : fp16 KV^T [B][C][M]       131,072 B
//   KSUM @ 1179648  : f32 [B][M]                  1,024 B
//   XKR  @ 1180672  : f32 [B][M][D]             262,144 B   (memset w/ KSUM)
//   WQB  @ 1442816  : fp16 [M][C] 16384 B
//   WKB  @ 1459200  : fp16 [M][C] 16384 B
//   QG   @ 1508352  : fp16 Q [B][N][M]         8,388,608 B  (un-normalized)
// d_out doubles as scratch before k_final overwrites it (stream-ordered):
//   [0, 33554432) bytes           xkpart fp16 [B][T=256][M][D=256]
//   [67108864, 100663296) bytes   enpart f32 [SPLIT=16][B][C][C]
#define XKPART_F32OFF 16777216ull   // float offset of enpart in d_out

#define GRAM_BLKS 384               // 3 * SPLIT * NB
#define KX_BLKS   2048              // 256 * NB

typedef short short4v __attribute__((ext_vector_type(4)));
typedef short short8 __attribute__((ext_vector_type(8)));
typedef _Float16 half8 __attribute__((ext_vector_type(8)));
typedef float f32x4 __attribute__((ext_vector_type(4)));

__device__ inline unsigned short f2h(float v) {
    return __builtin_bit_cast(unsigned short, (_Float16)v);   // 1 v_cvt op
}
__device__ inline float h2f(unsigned short h) {
    return (float)__builtin_bit_cast(_Float16, h);
}

__global__ void k_prep(const float* __restrict__ wq, const float* __restrict__ wk,
                       unsigned short* __restrict__ WQB, unsigned short* __restrict__ WKB)
{
    int i = blockIdx.x * 256 + threadIdx.x;   // 8192 total
    WQB[i] = f2h(wq[i]);
    WKB[i] = f2h(wk[i]);
}

// FUSED launch 1: blocks [0,384) = gram, [384,2432) = kx.
// Gram blocks XCD-SWIZZLED: bid -> (xcd=bid&7, slot=bid>>3),
// grp = xcd*16 + slot/3, tile = slot%3 — the 3 tiles of one (sp,b) group
// are temporally adjacent ON THE SAME XCD (shared panels hit L2), and each
// XCD serves exactly one batch b.
__global__ __launch_bounds__(256, 4) void k_work1(
    const float* __restrict__ x,
    const unsigned short* __restrict__ WKB, const unsigned short* __restrict__ WQB,
    const float* __restrict__ bk, const float* __restrict__ bq,
    unsigned short* __restrict__ xkpart, float* __restrict__ Ksum,
    unsigned short* __restrict__ Qg, float* __restrict__ enpart)
{
    __shared__ unsigned short ldsbuf[20480];   // 40960 B
    const int bid = blockIdx.x;
    const int tid = threadIdx.x;

    if (bid < GRAM_BLKS) {
        // ================= GRAM (staged fp16 MFMA, symmetry-aware) =========
        unsigned short* As = ldsbuf;            // 128*72
        unsigned short* Bs = ldsbuf + 9216;     // 128*72
        const int xcd = bid & 7, slot = bid >> 3;      // 48 slots per XCD
        const int grp = xcd * 16 + slot / 3;           // [0,128)
        const int tile = slot % 3;
        const int sp = grp & 15, b = grp >> 4;
        const int rt = (tile == 2) ? 1 : 0;
        const int ct = (tile == 0) ? 0 : 1;
        const bool diag = (rt == ct);
        const int r0 = rt * 128, c0 = ct * 128;
        const float* xb = x + (size_t)b * CH * NPIX;
        const int k0base = sp * KCH;

        unsigned short* Bs_p = diag ? As : Bs;

        const int wave = tid >> 6, lane = tid & 63;
        const int wr = wave >> 1, wc = wave & 1;

        f32x4 acc[4][4];
        #pragma unroll
        for (int i = 0; i < 4; ++i)
            #pragma unroll
            for (int j = 0; j < 4; ++j)
                acc[i][j] = (f32x4){0.f, 0.f, 0.f, 0.f};

        const int oct = tid & 7;
        const int frow = tid >> 3;

        for (int kk = 0; kk < KCH; kk += 64) {
            __syncthreads();
            const int k0 = k0base + kk;
            #pragma unroll
            for (int half = 0; half < 2; ++half) {
                if (half && diag) continue;
                const int rowbase = half ? c0 : r0;
                unsigned short* Hs = half ? Bs : As;
                #pragma unroll
                for (int s = 0; s < 4; ++s) {
                    const int r = frow + s * 32;
                    const float* src = xb + (size_t)(rowbase + r) * NPIX + k0 + oct * 8;
                    float4 v0 = *(const float4*)src;
                    float4 v1 = *(const float4*)(src + 4);
                    float vv[8] = {v0.x, v0.y, v0.z, v0.w, v1.x, v1.y, v1.z, v1.w};
                    short8 p;
                    #pragma unroll
                    for (int e = 0; e < 8; ++e) p[e] = (short)f2h(vv[e]);
                    *(short8*)&Hs[r * 72 + oct * 8] = p;
                }
            }
            __syncthreads();

            #pragma unroll
            for (int ks2 = 0; ks2 < 2; ++ks2) {
                short8 a4[4], b4[4];
                const int rbase = wr * 64 + (lane & 15);
                const int cbase = wc * 64 + (lane & 15);
                const int koff = ks2 * 32 + (lane >> 4) * 8;
                #pragma unroll
                for (int f = 0; f < 4; ++f) {
                    a4[f] = *(const short8*)&As[(rbase + f * 16) * 72 + koff];
                    b4[f] = *(const short8*)&Bs_p[(cbase + f * 16) * 72 + koff];
                }
                #pragma unroll
                for (int i = 0; i < 4; ++i)
                    #pragma unroll
                    for (int j = 0; j < 4; ++j)
                        acc[i][j] = __builtin_amdgcn_mfma_f32_16x16x32_f16(
                            __builtin_bit_cast(half8, a4[i]),
                            __builtin_bit_cast(half8, b4[j]), acc[i][j], 0, 0, 0);
            }
        }

        float* ep = enpart + (size_t)(sp * NB + b) * (CH * CH);
        const int rw = (lane >> 4) * 4;
        const int cw = lane & 15;
        #pragma unroll
        for (int i = 0; i < 4; ++i)
            #pragma unroll
            for (int j = 0; j < 4; ++j) {
                const int row = r0 + wr * 64 + i * 16 + rw;
                const int col = c0 + wc * 64 + j * 16 + cw;
                #pragma unroll
                for (int q = 0; q < 4; ++q) {
                    float v = acc[i][j][q];
                    ep[(size_t)(row + q) * CH + col] = v;
                    if (!diag) ep[(size_t)col * CH + (row + q)] = v;
                }
            }
    } else {
        // ================= KX (K+Q conv + XK partial) ======================
        unsigned short* xs  = ldsbuf;            // CH*72 = 18432 shorts
        unsigned short* ksm = ldsbuf + 18432;    // MDIM*64 = 2048 shorts
        const int u = bid - GRAM_BLKS;
        const int b = u >> 8, t = u & 255;
        const int n0 = t * 64;
        const int w = tid >> 6, l = tid & 63;
        const int li = l & 15, lg = l >> 4;
        const float* xb = x + (size_t)b * CH * NPIX;

        #pragma unroll
        for (int s = 0; s < 8; ++s) {
            int e8 = tid + s * 256;
            int c = e8 >> 3, j8 = e8 & 7;
            const float* src = xb + (size_t)c * NPIX + n0 + j8 * 8;
            float4 v0 = *(const float4*)src;
            float4 v1 = *(const float4*)(src + 4);
            float vv[8] = {v0.x, v0.y, v0.z, v0.w, v1.x, v1.y, v1.z, v1.w};
            short8 p;
            #pragma unroll
            for (int e = 0; e < 8; ++e) p[e] = (short)f2h(vv[e]);
            const int g = j8 ^ (c & 7) ^ ((c >> 3) & 7);
            *(short8*)&xs[c * 72 + g * 8] = p;
        }
        __syncthreads();

        {   // K + Q via f16 MFMA; wave w covers n = w*16 + li
            f32x4 accK[2], accQ[2];
            #pragma unroll
            for (int i = 0; i < 2; ++i) {
                accK[i] = (f32x4){0.f, 0.f, 0.f, 0.f};
                accQ[i] = (f32x4){0.f, 0.f, 0.f, 0.f};
            }
            const int n = w * 16 + li;
            const int gn = n >> 3, inn = n & 7;
            #pragma unroll
            for (int kc = 0; kc < 8; ++kc) {
                short8 bxw;
                #pragma unroll
                for (int e = 0; e < 8; ++e) {
                    const int d = kc * 32 + lg * 8 + e;
                    const int g = gn ^ e ^ ((kc * 4 + lg) & 7);
                    bxw[e] = (short)xs[d * 72 + g * 8 + inn];
                }
                half8 bx = __builtin_bit_cast(half8, bxw);
                #pragma unroll
                for (int i = 0; i < 2; ++i) {
                    const size_t wo = (size_t)(i * 16 + li) * CH + kc * 32 + lg * 8;
                    half8 kw = __builtin_bit_cast(half8, *(const short8*)(WKB + wo));
                    half8 qw = __builtin_bit_cast(half8, *(const short8*)(WQB + wo));
                    accK[i] = __builtin_amdgcn_mfma_f32_16x16x32_f16(kw, bx, accK[i], 0, 0, 0);
                    accQ[i] = __builtin_amdgcn_mfma_f32_16x16x32_f16(qw, bx, accQ[i], 0, 0, 0);
                }
            }
            unsigned short* qp = Qg + ((size_t)b * NPIX + n0 + n) * MDIM;
            #pragma unroll
            for (int i = 0; i < 2; ++i) {
                short4v q4;
                #pragma unroll
                for (int q = 0; q < 4; ++q) {
                    const int m = i * 16 + lg * 4 + q;
                    float kv = accK[i][q] + bk[m];
                    kv = fmaxf(kv, 0.f) + log1pf(expf(-fabsf(kv)));  // softplus
                    ksm[m * 64 + (n ^ ((m & 7) << 3))] = f2h(kv);
                    float qv = accQ[i][q] + bq[m];
                    qv = fmaxf(qv, 0.f) + log1pf(expf(-fabsf(qv)));  // softplus
                    q4[q] = (short)f2h(qv);
                }
                *(short4v*)(qp + i * 16 + lg * 4) = q4;
            }
        }
        __syncthreads();

        if (tid < MDIM) {
            float s = 0.f;
            #pragma unroll
            for (int j = 0; j < 64; ++j)
                s += h2f(ksm[tid * 64 + (j ^ ((tid & 7) << 3))]);
            atomicAdd(&Ksum[b * MDIM + tid], s);
        }

        f32x4 axk[4][2];
        #pragma unroll
        for (int i = 0; i < 4; ++i)
            #pragma unroll
            for (int j = 0; j < 2; ++j) axk[i][j] = (f32x4){0.f, 0.f, 0.f, 0.f};

        #pragma unroll
        for (int ks2 = 0; ks2 < 2; ++ks2) {
            const int nc = ks2 * 32 + lg * 8;
            half8 kfr[2];
            #pragma unroll
            for (int j = 0; j < 2; ++j) {
                const int m = j * 16 + li;
                kfr[j] = __builtin_bit_cast(half8,
                    *(const short8*)&ksm[m * 64 + (nc ^ ((m & 7) << 3))]);
            }
            #pragma unroll
            for (int i = 0; i < 4; ++i) {
                const int d = w * 64 + i * 16 + li;
                const int g = (nc >> 3) ^ (d & 7) ^ ((d >> 3) & 7);
                half8 xf = __builtin_bit_cast(half8, *(const short8*)&xs[d * 72 + g * 8]);
                #pragma unroll
                for (int j = 0; j < 2; ++j)
                    axk[i][j] = __builtin_amdgcn_mfma_f32_16x16x32_f16(xf, kfr[j], axk[i][j], 0, 0, 0);
            }
        }

        unsigned short* xkp = xkpart + (size_t)(b * 256 + t) * MDIM * CH;
        #pragma unroll
        for (int i = 0; i < 4; ++i)
            #pragma unroll
            for (int j = 0; j < 2; ++j) {
                short4v pk;
                #pragma unroll
                for (int q = 0; q < 4; ++q) pk[q] = (short)f2h(axk[i][j][q]);
                *(short4v*)(xkp + (size_t)(j * 16 + li) * CH + w * 64 + i * 16 + lg * 4) = pk;
            }
    }
}

// FUSED launch 2: blocks [0,1024) = xkreduce, [1024,3072) = softmax.
__global__ void k_work2(const unsigned short* __restrict__ xkpart,
                        float* __restrict__ XKR,
                        const float* __restrict__ enpart,
                        const float* __restrict__ gc,
                        unsigned short* __restrict__ attnb)
{
    __shared__ float red[8];
    const int bid = blockIdx.x;
    if (bid < 1024) {
        // ---- xkreduce: 4-way t-split over fp16 partials ----
        const int bx = bid & 255;
        const int b = bx >> 5, m = bx & 31, d = threadIdx.x;
        const int t0 = (bid >> 8) * 64;
        float s = 0.f;
        #pragma unroll 4
        for (int t = t0; t < t0 + 64; ++t)
            s += h2f(xkpart[(((size_t)b * 256 + t) * MDIM + m) * CH + d]);
        atomicAdd(&XKR[((size_t)b * MDIM + m) * CH + d], s);
    } else {
        // ---- softmin over summed partials; emits fp16 (gc*attn) ----
        const int bid2 = bid - 1024;
        const int b = bid2 >> 8, c = bid2 & 255;
        const int d = threadIdx.x;
        float e = 0.f;
        #pragma unroll
        for (int sp = 0; sp < SPLIT; ++sp)
            e += enpart[(size_t)(sp * NB + b) * (CH * CH) + (size_t)c * CH + d];
        float mn = e;
        #pragma unroll
        for (int o = 1; o < 64; o <<= 1) mn = fminf(mn, __shfl_xor(mn, o));
        if ((d & 63) == 0) red[d >> 6] = mn;
        __syncthreads();
        mn = fminf(fminf(red[0], red[1]), fminf(red[2], red[3]));
        float w = expf(mn - e);
        float s = w;
        #pragma unroll
        for (int o = 1; o < 64; o <<= 1) s += __shfl_xor(s, o);
        if ((d & 63) == 0) red[4 + (d >> 6)] = s;
        __syncthreads();
        s = red[4] + red[5] + red[6] + red[7];
        attnb[((size_t)(b * CH) + c) * CH + d] = f2h(gc[0] * w / s);
    }
}

// KV^T[c][m] = sum_d wv[c][d]*XKR[m][d] + bv[c]*Ksum[m] — f16 MFMA.
__global__ void k_kv(const float* __restrict__ wv, const float* __restrict__ bv,
                     const float* __restrict__ XKR, const float* __restrict__ Ksum,
                     unsigned short* __restrict__ KVTb) {
    const int b = blockIdx.x, tid = threadIdx.x;
    const int w = tid >> 6, l = tid & 63;
    const int li = l & 15, lg = l >> 4;

    f32x4 acc[4][2];   // i: c-16blocks in wave's 64c; j: m-16blocks
    #pragma unroll
    for (int i = 0; i < 4; ++i)
        #pragma unroll
        for (int j = 0; j < 2; ++j) acc[i][j] = (f32x4){0.f, 0.f, 0.f, 0.f};

    for (int kk = 0; kk < CH; kk += 32) {
        half8 bfr[2];
        #pragma unroll
        for (int j = 0; j < 2; ++j) {
            const int m = j * 16 + li;
            const float* sp = XKR + ((size_t)b * MDIM + m) * CH + kk + lg * 8;
            float4 v0 = *(const float4*)sp;
            float4 v1 = *(const float4*)(sp + 4);
            bfr[j][0] = (_Float16)v0.x; bfr[j][1] = (_Float16)v0.y;
            bfr[j][2] = (_Float16)v0.z; bfr[j][3] = (_Float16)v0.w;
            bfr[j][4] = (_Float16)v1.x; bfr[j][5] = (_Float16)v1.y;
            bfr[j][6] = (_Float16)v1.z; bfr[j][7] = (_Float16)v1.w;
        }
        #pragma unroll
        for (int i = 0; i < 4; ++i) {
            const int c = w * 64 + i * 16 + li;
            const float* wp = wv + (size_t)c * CH + kk + lg * 8;
            float4 w0 = *(const float4*)wp;
            float4 w1 = *(const float4*)(wp + 4);
            half8 afr;
            afr[0] = (_Float16)w0.x; afr[1] = (_Float16)w0.y;
            afr[2] = (_Float16)w0.z; afr[3] = (_Float16)w0.w;
            afr[4] = (_Float16)w1.x; afr[5] = (_Float16)w1.y;
            afr[6] = (_Float16)w1.z; afr[7] = (_Float16)w1.w;
            #pragma unroll
            for (int j = 0; j < 2; ++j)
                acc[i][j] = __builtin_amdgcn_mfma_f32_16x16x32_f16(afr, bfr[j], acc[i][j], 0, 0, 0);
        }
    }

    // D: row = c (lg*4+q within 16-block), col = m (li)
    #pragma unroll
    for (int i = 0; i < 4; ++i)
        #pragma unroll
        for (int j = 0; j < 2; ++j) {
            const int m = j * 16 + li;
            const float ks = Ksum[b * MDIM + m];
            #pragma unroll
            for (int q = 0; q < 4; ++q) {
                const int c = w * 64 + i * 16 + lg * 4 + q;
                KVTb[((size_t)b * CH + c) * MDIM + m] =
                    f2h(acc[i][j][q] + bv[c] * ks);
            }
        }
}

// out = x + (nrm·Q)^T·KV + (gc·attn)·X — fp16 operands, f16 MFMAs.
__global__ __launch_bounds__(256, 4) void k_final(
    const float* __restrict__ x, const unsigned short* __restrict__ Qg,
    const unsigned short* __restrict__ KVTb, const float* __restrict__ Ksum,
    const unsigned short* __restrict__ attnb, const float* __restrict__ gk,
    float* __restrict__ out)
{
    __shared__ uint2 xsTv[4096];            // 32 KB: fp16 xT [n=64][d=256] swizzled
    unsigned char* xsT = (unsigned char*)xsTv;
    const int b = blockIdx.y, n0 = blockIdx.x * 64, tid = threadIdx.x;
    const int w = tid >> 6, l = tid & 63;
    const int li = l & 15, lg = l >> 4;
    const float* xb = x + (size_t)b * CH * NPIX;

    // ---- issue Q fragment loads + Ksum loads (in flight during staging) ----
    short8 qb[4];
    #pragma unroll
    for (int j = 0; j < 4; ++j)
        qb[j] = *(const short8*)(Qg +
            ((size_t)b * NPIX + n0 + j * 16 + li) * MDIM + lg * 8);
    float4 ks0 = *(const float4*)(Ksum + b * MDIM + lg * 8);
    float4 ks1 = *(const float4*)(Ksum + b * MDIM + lg * 8 + 4);
    const float kse[8] = {ks0.x + EPSF, ks0.y + EPSF, ks0.z + EPSF, ks0.w + EPSF,
                          ks1.x + EPSF, ks1.y + EPSF, ks1.z + EPSF, ks1.w + EPSF};

    // ---- stage xT ----
    {
        const int n4 = li * 4;
        const bool o1 = lg & 1, o2 = (lg >> 1) & 1;
        #pragma unroll 4
        for (int p = 0; p < 16; ++p) {
            const int d0 = w * 64 + p * 4;
            float4 vv = *(const float4*)(xb + (size_t)(d0 + lg) * NPIX + n0 + n4);
            float v0 = vv.x, v1 = vv.y, v2 = vv.z, v3 = vv.w;
            float r1 = __shfl_xor(o1 ? v0 : v1, 16);
            float r2 = __shfl_xor(o1 ? v2 : v3, 16);
            float a0 = o1 ? r1 : v0, a1 = o1 ? v1 : r1;
            float a2 = o1 ? r2 : v2, a3 = o1 ? v3 : r2;
            float r3 = __shfl_xor(o2 ? a0 : a2, 32);
            float r4 = __shfl_xor(o2 ? a1 : a3, 32);
            float b0 = o2 ? r3 : a0, b1 = o2 ? r4 : a1;
            float b2 = o2 ? a2 : r3, b3 = o2 ? a3 : r4;
            const int nl = n4 + lg;
            unsigned lo = (unsigned)f2h(b0) | ((unsigned)f2h(b1) << 16);
            unsigned hi = (unsigned)f2h(b2) | ((unsigned)f2h(b3) << 16);
            const int off = nl * 512 +
                ((2 * d0) ^ ((nl & 7) << 4) ^ (((nl >> 3) & 1) << 3));
            *(uint2*)(xsT + off) = make_uint2(lo, hi);
        }
    }

    f32x4 acc[4][4];   // acc[i][j]: rows = n-block j, cols = c-block i
    #pragma unroll
    for (int i = 0; i < 4; ++i)
        #pragma unroll
        for (int j = 0; j < 4; ++j)
            acc[i][j] = (f32x4){0.f, 0.f, 0.f, 0.f};

    // ---- KAM (pre-barrier: no LDS dependence) ----
    {
        const float gkv = gk[0];
        half8 qs[4];
        #pragma unroll
        for (int j = 0; j < 4; ++j) {
            float qf[8];
            float den = 0.f;
            #pragma unroll
            for (int e = 0; e < 8; ++e) {
                qf[e] = h2f((unsigned short)qb[j][e]);
                den = fmaf(qf[e], kse[e], den);
            }
            den += __shfl_xor(den, 16);
            den += __shfl_xor(den, 32);
            const float nrm = gkv / den;
            #pragma unroll
            for (int e = 0; e < 8; ++e) qs[j][e] = (_Float16)(qf[e] * nrm);
        }
        #pragma unroll
        for (int i = 0; i < 4; ++i) {
            half8 ka = __builtin_bit_cast(half8, *(const short8*)(KVTb +
                ((size_t)b * CH + w * 64 + i * 16 + li) * MDIM + lg * 8));
            #pragma unroll
            for (int j = 0; j < 4; ++j)
                acc[i][j] = __builtin_amdgcn_mfma_f32_16x16x32_f16(qs[j], ka, acc[i][j], 0, 0, 0);
        }
    }
    __syncthreads();

    // ---- CAM: acc += X^T · (gc·attn)^T ----
    const unsigned short* ab = attnb + (size_t)b * CH * CH;
    for (int kk = 0; kk < CH; kk += 32) {
        half8 bx[4];
        #pragma unroll
        for (int j = 0; j < 4; ++j) {
            const int nf = j * 16 + li;
            const int d2 = 2 * (kk + lg * 8);
            const int sw = ((nf & 7) << 4) ^ (((nf >> 3) & 1) << 3);
            uint2 h0 = *(const uint2*)(xsT + nf * 512 + (d2 ^ sw));
            uint2 h1 = *(const uint2*)(xsT + nf * 512 + ((d2 + 8) ^ sw));
            int4 tmp = make_int4(h0.x, h0.y, h1.x, h1.y);
            bx[j] = __builtin_bit_cast(half8, tmp);
        }
        #pragma unroll
        for (int i = 0; i < 4; ++i) {
            half8 af = __builtin_bit_cast(half8, *(const short8*)(ab +
                (size_t)(w * 64 + i * 16 + li) * CH + kk + lg * 8));
            #pragma unroll
            for (int j = 0; j < 4; ++j)
                acc[i][j] = __builtin_amdgcn_mfma_f32_16x16x32_f16(bx[j], af, acc[i][j], 0, 0, 0);
        }
    }

    // ---- epilogue: out = x + acc, float4 per (i,j) ----
    float* outb = out + (size_t)b * CH * NPIX;
    #pragma unroll
    for (int i = 0; i < 4; ++i) {
        const int c = w * 64 + i * 16 + li;
        #pragma unroll
        for (int j = 0; j < 4; ++j) {
            const size_t idx = (size_t)c * NPIX + n0 + j * 16 + lg * 4;
            float4 xv = *(const float4*)(xb + idx);
            float4 v = make_float4(xv.x + acc[i][j][0], xv.y + acc[i][j][1],
                                   xv.z + acc[i][j][2], xv.w + acc[i][j][3]);
            *(float4*)(outb + idx) = v;
        }
    }
}

extern "C" void kernel_launch(void* const* d_in, const int* in_sizes, int n_in,
                              void* d_out, int out_size, void* d_ws, size_t ws_size,
                              hipStream_t stream)
{
    const float* x  = (const float*)d_in[0];
    const float* wq = (const float*)d_in[1];
    const float* bq = (const float*)d_in[2];
    const float* wk = (const float*)d_in[3];
    const float* bk = (const float*)d_in[4];
    const float* wv = (const float*)d_in[5];
    const float* bv = (const float*)d_in[6];
    const float* gk = (const float*)d_in[7];
    const float* gc = (const float*)d_in[8];
    float* out = (float*)d_out;
    char* wsb = (char*)d_ws;

    unsigned short* ATTB = (unsigned short*)(wsb);
    unsigned short* KVTB = (unsigned short*)(wsb + 1048576);
    float* KSUM = (float*)(wsb + 1179648);
    float* XKR  = (float*)(wsb + 1180672);
    unsigned short* WQB = (unsigned short*)(wsb + 1442816);
    unsigned short* WKB = (unsigned short*)(wsb + 1459200);
    unsigned short* QG  = (unsigned short*)(wsb + 1508352);

    unsigned short* xkpart = (unsigned short*)out;   // d_out scratch (fp16 partials)
    float* enpart = out + XKPART_F32OFF;

    // zero KSUM (1 KB) + XKR (256 KB) — contiguous
    hipMemsetAsync(KSUM, 0, 1024 + 262144, stream);

    k_prep<<<dim3(32), dim3(256), 0, stream>>>(wq, wk, WQB, WKB);
    k_work1<<<dim3(GRAM_BLKS + KX_BLKS), dim3(256), 0, stream>>>(
        x, WKB, WQB, bk, bq, xkpart, KSUM, QG, enpart);
    k_work2<<<dim3(3072), dim3(256), 0, stream>>>(xkpart, XKR, enpart, gc, ATTB);
    k_kv<<<dim3(NB), dim3(256), 0, stream>>>(wv, bv, XKR, KSUM, KVTB);
    k_final<<<dim3(NPIX / 64, NB), dim3(256), 0, stream>>>(x, QG, KVTB, KSUM,
                                                           ATTB, gk, out);
}